// Round 1
// baseline (594.608 us; speedup 1.0000x reference)
//
#include <hip/hip_runtime.h>

typedef unsigned short ushort_t;
typedef unsigned int uint_t;
typedef __attribute__((ext_vector_type(8))) short bf16x8;
typedef __attribute__((ext_vector_type(4))) float floatx4;
typedef __attribute__((ext_vector_type(16))) float floatx16;

#define SEQ 2048
#define DIM 4096
#define NH 32
#define NKV 8
#define HD 128
#define KVDIM 1024
#define QKVN 6144  // DIM + 2*KVDIM

__device__ __forceinline__ ushort_t f2b(float f) {
  union { float f; uint_t u; } x; x.f = f;
  uint_t u = x.u;
  u += 0x7fffu + ((u >> 16) & 1u);  // round-to-nearest-even
  return (ushort_t)(u >> 16);
}

#define GLOAD_LDS(g, l) \
  __builtin_amdgcn_global_load_lds((const __attribute__((address_space(1))) void*)(g), \
                                   (__attribute__((address_space(3))) void*)(l), 16, 0, 0)

#define BARX() asm volatile("s_barrier" ::: "memory")
#define WAIT_VM(n) asm volatile("s_waitcnt vmcnt(" #n ")" ::: "memory")

// ---------------- all f32 -> bf16 converts in one kernel ----------------
__global__ __launch_bounds__(256) void cvt_all(const float* __restrict__ x,
                                               const float* __restrict__ wq,
                                               const float* __restrict__ wk,
                                               const float* __restrict__ wv,
                                               const float* __restrict__ wo,
                                               ushort_t* __restrict__ xb,
                                               ushort_t* __restrict__ wqkvb,
                                               ushort_t* __restrict__ wob) {
  int b = blockIdx.x;
  const float* src; ushort_t* dst; int i;
  if (b < 4096)       { src = x;  dst = xb;               i = b * 256 + threadIdx.x; }
  else if (b < 12288) { src = wq; dst = wqkvb;            i = (b - 4096) * 256 + threadIdx.x; }
  else if (b < 14336) { src = wk; dst = wqkvb + 16777216; i = (b - 12288) * 256 + threadIdx.x; }
  else if (b < 16384) { src = wv; dst = wqkvb + 20971520; i = (b - 14336) * 256 + threadIdx.x; }
  else                { src = wo; dst = wob;              i = (b - 16384) * 256 + threadIdx.x; }
  const float4* s = (const float4*)src;
  float4 a = s[2 * i], c = s[2 * i + 1];
  union { ushort_t u[8]; uint4 v; } o;
  o.u[0] = f2b(a.x); o.u[1] = f2b(a.y); o.u[2] = f2b(a.z); o.u[3] = f2b(a.w);
  o.u[4] = f2b(c.x); o.u[5] = f2b(c.y); o.u[6] = f2b(c.z); o.u[7] = f2b(c.w);
  ((uint4*)dst)[i] = o.v;
}

// ---------------- bf16 GEMM, 8-phase counted-vmcnt schedule ----------------
// C f32[M][N] = A[M][K] * B[N][K]^T.  BM=128, BN=256, BK=64.
// 512 threads = 8 waves (2 M x 4 N), wave tile 64x64, 16x16x32 MFMA.
// LDS: double-buffered A(128x64) + B(256x64), chunk^(row&7) swizzle, 96 KiB.
// Per iteration: 2 K-tiles, 8 phases {ds_read | stage-issue | bar | setprio+8 MFMA | bar},
// vmcnt(6)/vmcnt(4) only at phases 4/8 (loads stay in flight across barriers).
// Stage targets are always >=1 full barrier-phase after the region's last ds_read.
__global__ __launch_bounds__(512, 2) void gemm8p(const ushort_t* __restrict__ A,
                                                 const ushort_t* __restrict__ B,
                                                 float* __restrict__ C,
                                                 int N, int K) {
  __shared__ __attribute__((aligned(16))) ushort_t sA[2][8192];   // [slot][128 rows][64]
  __shared__ __attribute__((aligned(16))) ushort_t sB[2][16384];  // [slot][256 rows][64]

  int tid = threadIdx.x;
  int lane = tid & 63;
  int w = tid >> 6;
  int wm = w >> 2, wn = w & 3;          // 2 x 4 waves
  int l15 = lane & 15, l4 = lane >> 4;
  int e7 = l15 & 7;
  int co0 = ((l4 ^ e7) << 3);           // swizzled frag offset, ks=0
  int co1 = co0 ^ 32;                   // ks=1

  // XCD-aware bijective block swizzle (gridDim.x % 8 == 0 for both launches)
  int nwg = (int)gridDim.x;
  int ntn = N >> 8;
  int lin = ((int)blockIdx.x & 7) * (nwg >> 3) + ((int)blockIdx.x >> 3);
  int m0 = (lin / ntn) << 7;
  int n0 = (lin % ntn) << 8;

  int nkt = K >> 6;
  int niter = nkt >> 1;

  // staging: thread tid, load e -> LDS chunk (e*512+tid)*16B (linear, wave-uniform base);
  // global source col pre-swizzled so that read-side chunk^(row&7) matches.
  int r0 = tid >> 3;
  int c0 = ((tid & 7) ^ (r0 & 7)) << 3;
  const ushort_t* sa0 = A + (size_t)(m0 + r0) * K + c0;
  const ushort_t* sb0 = B + (size_t)(n0 + r0) * K + c0;
  const ushort_t* sb1 = sb0 + (size_t)128 * K;
  int d0 = (tid & ~63) << 3;            // wave-uniform LDS elem offset, e=0
  size_t ek = (size_t)64 * K;

#define STA(kk, s)  do { GLOAD_LDS(sa0 + (kk), &sA[s][d0]); \
                         GLOAD_LDS(sa0 + ek + (kk), &sA[s][d0 + 4096]); } while (0)
#define STB0(kk, s) do { GLOAD_LDS(sb0 + (kk), &sB[s][d0]); \
                         GLOAD_LDS(sb0 + ek + (kk), &sB[s][d0 + 4096]); } while (0)
#define STB1(kk, s) do { GLOAD_LDS(sb1 + (kk), &sB[s][8192 + d0]); \
                         GLOAD_LDS(sb1 + ek + (kk), &sB[s][8192 + d0 + 4096]); } while (0)

  floatx4 acc[4][4] = {};
  bf16x8 a[4][2], b[4][2];

#define RDA2(s, RG) do { const ushort_t* pa = &sA[s][(wm * 64 + l15) * 64]; \
  _Pragma("unroll") for (int rg = 0; rg < 2; ++rg) { \
    a[RG + rg][0] = *(const bf16x8*)&pa[(RG + rg) * 1024 + co0]; \
    a[RG + rg][1] = *(const bf16x8*)&pa[(RG + rg) * 1024 + co1]; } } while (0)
#define RDB2(s, CG) do { const ushort_t* pb = &sB[s][(wn * 64 + l15) * 64]; \
  _Pragma("unroll") for (int cg = 0; cg < 2; ++cg) { \
    b[CG + cg][0] = *(const bf16x8*)&pb[(CG + cg) * 1024 + co0]; \
    b[CG + cg][1] = *(const bf16x8*)&pb[(CG + cg) * 1024 + co1]; } } while (0)

#define QUAD(RG, CG) do { __builtin_amdgcn_s_setprio(1); \
  _Pragma("unroll") for (int rg = 0; rg < 2; ++rg) \
  _Pragma("unroll") for (int cg = 0; cg < 2; ++cg) \
  _Pragma("unroll") for (int ks = 0; ks < 2; ++ks) \
    acc[RG + rg][CG + cg] = __builtin_amdgcn_mfma_f32_16x16x32_bf16( \
        a[RG + rg][ks], b[CG + cg][ks], acc[RG + rg][CG + cg], 0, 0, 0); \
  __builtin_amdgcn_s_setprio(0); } while (0)

  // prologue: tile0 {A,B0,B1} -> slot0, tile1 {A,B0} -> slot1 (10 loads);
  // wait until tile0 (6 loads) landed -> vmcnt(4)
  STA(0, 0); STB0(0, 0); STB1(0, 0);
  STA(64, 1); STB0(64, 1);
  WAIT_VM(4);
  BARX();

#pragma unroll 1
  for (int i = 0; i < niter; ++i) {
    int k1 = (2 * i + 1) << 6;
    int t2 = 2 * i + 2; if (t2 > nkt - 1) t2 = nkt - 1;   // overrun stages: clamped,
    int t3 = 2 * i + 3; if (t3 > nkt - 1) t3 = nkt - 1;   // land in never-read regions
    int k2 = t2 << 6, k3 = t3 << 6;

    // ---------------- tile 2i (slot 0) ----------------
    // P1: read all A + B-half0 of slot0; stage tile(2i+1).B1 -> slot1 (free)
    RDA2(0, 0); RDB2(0, 0); RDA2(0, 2);
    STB1(k1, 1);
    BARX(); QUAD(0, 0); BARX();
    // P2: read B-half1; stage tile(2i+2).A -> slot0-A (last read P1)
    RDB2(0, 2);
    STA(k2, 0);
    BARX(); QUAD(0, 2); BARX();
    // P3: stage tile(2i+2).B0 -> slot0-B0 (last read P2)
    STB0(k2, 0);
    BARX(); QUAD(2, 0); BARX();
    // P4: stage tile(2i+2).B1; wait tiles..2i+1 landed (3 units in flight)
    STB1(k2, 0);
    WAIT_VM(6);
    BARX(); QUAD(2, 2); BARX();

    // ---------------- tile 2i+1 (slot 1) ----------------
    // P5: read all A + B-half0 of slot1 (no stage)
    RDA2(1, 0); RDB2(1, 0); RDA2(1, 2);
    BARX(); QUAD(0, 0); BARX();
    // P6: read B-half1; stage tile(2i+3).A -> slot1-A (last read P5)
    RDB2(1, 2);
    STA(k3, 1);
    BARX(); QUAD(0, 2); BARX();
    // P7: stage tile(2i+3).B0 -> slot1-B0 (last read P6)
    STB0(k3, 1);
    BARX(); QUAD(2, 0); BARX();
    // P8: wait tiles..2i+2 landed (2 units in flight); tile(2i+3).B1 staged next P1
    WAIT_VM(4);
    BARX(); QUAD(2, 2); BARX();
  }

  // epilogue: C/D layout col=lane&15, row=(lane>>4)*4+reg
#pragma unroll
  for (int rg = 0; rg < 4; ++rg)
#pragma unroll
    for (int cg = 0; cg < 4; ++cg) {
      float* cp = C + (size_t)(m0 + wm * 64 + rg * 16 + l4 * 4) * N
                    + (n0 + wn * 64 + cg * 16 + l15);
#pragma unroll
      for (int r = 0; r < 4; ++r) cp[(size_t)r * N] = acc[rg][cg][r];
    }
#undef STA
#undef STB0
#undef STB1
#undef RDA2
#undef RDB2
#undef QUAD
}

// ---------------- rope_q + rope_k + zero_tail fused (branch by block) ----------------
__global__ __launch_bounds__(256) void posteps(const float* __restrict__ qkv,
                                               const float* __restrict__ cosf,
                                               const float* __restrict__ sinf,
                                               ushort_t* __restrict__ qb,
                                               ushort_t* __restrict__ kb,
                                               float* __restrict__ out) {
  int b = blockIdx.x;
  if (b < 16384) {  // rope_q, pre-scaled by log2(e)/sqrt(128)
    const float QS = 1.4426950408889634f * 0.08838834764831845f;
    int idx = b * 256 + threadIdx.x;
    int pos = idx >> 11;
    int p = idx & 2047;
    int h = p >> 6, i = p & 63;
    size_t sb = (size_t)pos * QKVN + h * HD + 2 * i;
    float x1 = qkv[sb], x2 = qkv[sb + 1];
    float c = cosf[pos * 64 + i], s = sinf[pos * 64 + i];
    float r1 = (x1 * c - x2 * s) * QS;
    float r2 = (x1 * s + x2 * c) * QS;
    size_t db = (size_t)pos * DIM + h * HD + 2 * i;
    ((uint_t*)qb)[db >> 1] = (uint_t)f2b(r1) | ((uint_t)f2b(r2) << 16);
  } else if (b < 20480) {  // rope_k + cache_k
    int idx = (b - 16384) * 256 + threadIdx.x;
    int pos = idx >> 9;
    int p = idx & 511;
    int kvh = p >> 6, i = p & 63;
    size_t sb = (size_t)pos * QKVN + DIM + kvh * HD + 2 * i;
    float x1 = qkv[sb], x2 = qkv[sb + 1];
    float c = cosf[pos * 64 + i], s = sinf[pos * 64 + i];
    float r1 = x1 * c - x2 * s;
    float r2 = x1 * s + x2 * c;
    size_t db = (size_t)pos * KVDIM + kvh * HD + 2 * i;
    ((uint_t*)kb)[db >> 1] = (uint_t)f2b(r1) | ((uint_t)f2b(r2) << 16);
    float2 cv; cv.x = r1; cv.y = r2;
    ((float2*)(out + 8388608))[db >> 1] = cv;  // cache_k base
  } else {  // zero tails of both caches
    int i = (b - 20480) * 256 + threadIdx.x;
    float4 z = {0.f, 0.f, 0.f, 0.f};
    ((float4*)(out + 10485760))[i] = z;  // cache_k rows 2048..4095
    ((float4*)(out + 14680064))[i] = z;  // cache_v rows 2048..4095
  }
}

// ---------------- V: cache_v f32 copy + transposed bf16 Vt[kvh][d][pos] ----------------
__global__ __launch_bounds__(256) void vt_cache(const float* __restrict__ qkv,
                                                ushort_t* __restrict__ vtb,
                                                float* __restrict__ cache_v) {
  __shared__ float tile[64][65];
  int pos0 = blockIdx.x * 64, c0 = blockIdx.y * 64;
  int t = threadIdx.x;
  int pr = t >> 4, cq = (t & 15) * 4;
#pragma unroll
  for (int rr = 0; rr < 4; ++rr) {
    int prow = pr + rr * 16;
    float4 v = *(const float4*)(qkv + (size_t)(pos0 + prow) * QKVN + DIM + KVDIM + c0 + cq);
    *(float4*)(cache_v + (size_t)(pos0 + prow) * KVDIM + c0 + cq) = v;
    tile[prow][cq] = v.x; tile[prow][cq + 1] = v.y;
    tile[prow][cq + 2] = v.z; tile[prow][cq + 3] = v.w;
  }
  __syncthreads();
  int dc = t >> 2, pg = (t & 3) * 16;
  int kvh = c0 >> 7, dl = (c0 & 127) + dc;
  union { ushort_t u[16]; uint4 q[2]; } o;
#pragma unroll
  for (int e = 0; e < 16; ++e) o.u[e] = f2b(tile[pg + e][dc]);
  uint4* dst = (uint4*)(vtb + (size_t)kvh * (HD * SEQ) + (size_t)dl * SEQ + pos0 + pg);
  dst[0] = o.q[0]; dst[1] = o.q[1];
}

// ---------------- flash attention: causal, GQA 4:1, pair-balanced ----------------
__global__ __launch_bounds__(256) void attn(const ushort_t* __restrict__ Q,
                                            const ushort_t* __restrict__ Kb,
                                            const ushort_t* __restrict__ Vt,
                                            ushort_t* __restrict__ O) {
  int h = blockIdx.y;
  int kvh = h >> 2;
  int tid = threadIdx.x;
  int w = tid >> 6, lane = tid & 63;
  int row = lane & 15, quad = lane >> 4;

  __shared__ __attribute__((aligned(16))) ushort_t lds_k[64][136];
  __shared__ __attribute__((aligned(16))) ushort_t lds_vt[128][72];
  __shared__ __attribute__((aligned(16))) float p_lds[4][16][68];

  int kr = tid >> 2, kc = (tid & 3) * 32;
  int vd = tid >> 1, vj = (tid & 1) * 32;
  const ushort_t* kg = Kb + (size_t)kr * KVDIM + kvh * HD + kc;
  const ushort_t* vg = Vt + (size_t)kvh * (HD * SEQ) + (size_t)vd * SEQ + vj;

#pragma unroll 1
  for (int ph = 0; ph < 2; ++ph) {
    int qb = ph ? (31 - blockIdx.x) : blockIdx.x;
    int q0 = qb * 64 + w * 16;

    bf16x8 qf[4];
    const ushort_t* qp = Q + (size_t)(q0 + row) * DIM + h * HD + quad * 8;
#pragma unroll
    for (int ks = 0; ks < 4; ++ks) qf[ks] = *(const bf16x8*)(qp + ks * 32);

    floatx4 o_acc[8] = {};
    float l_r[4] = {0.f, 0.f, 0.f, 0.f};

    for (int kt = 0; kt <= qb; ++kt) {
      int kv0 = kt * 64;
#pragma unroll
      for (int e = 0; e < 4; ++e)
        *(bf16x8*)&lds_k[kr][kc + e * 8] = *(const bf16x8*)(kg + (size_t)kv0 * KVDIM + e * 8);
#pragma unroll
      for (int e = 0; e < 4; ++e)
        *(bf16x8*)&lds_vt[vd][vj + e * 8] = *(const bf16x8*)(vg + kv0 + e * 8);
      __syncthreads();

      floatx4 s[4] = {};
#pragma unroll
      for (int j2 = 0; j2 < 4; ++j2)
#pragma unroll
        for (int ks = 0; ks < 4; ++ks) {
          bf16x8 kfrag = *(const bf16x8*)&lds_k[j2 * 16 + row][ks * 32 + quad * 8];
          s[j2] = __builtin_amdgcn_mfma_f32_16x16x32_bf16(qf[ks], kfrag, s[j2], 0, 0, 0);
        }

      bool diag = (kt == qb);
      float pv[4][4];
#pragma unroll
      for (int j2 = 0; j2 < 4; ++j2)
#pragma unroll
        for (int r = 0; r < 4; ++r) {
          float v = s[j2][r];
          if (diag) {
            int j_g = kv0 + j2 * 16 + row;
            int i_g = q0 + quad * 4 + r;
            v += (j_g <= i_g) ? 0.f : -1e9f;
          }
          float p = exp2f(v);
          pv[j2][r] = p;
          l_r[r] += p;
        }
#pragma unroll
      for (int j2 = 0; j2 < 4; ++j2)
#pragma unroll
        for (int r = 0; r < 4; ++r) p_lds[w][quad * 4 + r][j2 * 16 + row] = pv[j2][r];
      bf16x8 pf[2];
#pragma unroll
      for (int kb2 = 0; kb2 < 2; ++kb2) {
        float4 pa = *(const float4*)&p_lds[w][row][kb2 * 32 + quad * 8];
        float4 pb = *(const float4*)&p_lds[w][row][kb2 * 32 + quad * 8 + 4];
        union { bf16x8 v; ushort_t u[8]; } pu;
        pu.u[0] = f2b(pa.x); pu.u[1] = f2b(pa.y); pu.u[2] = f2b(pa.z); pu.u[3] = f2b(pa.w);
        pu.u[4] = f2b(pb.x); pu.u[5] = f2b(pb.y); pu.u[6] = f2b(pb.z); pu.u[7] = f2b(pb.w);
        pf[kb2] = pu.v;
      }
#pragma unroll
      for (int db = 0; db < 8; ++db)
#pragma unroll
        for (int kb2 = 0; kb2 < 2; ++kb2) {
          bf16x8 vfrag = *(const bf16x8*)&lds_vt[db * 16 + row][kb2 * 32 + quad * 8];
          o_acc[db] = __builtin_amdgcn_mfma_f32_16x16x32_bf16(pf[kb2], vfrag, o_acc[db], 0, 0, 0);
        }
      __syncthreads();
    }

#pragma unroll
    for (int off = 1; off < 16; off <<= 1)
#pragma unroll
      for (int r = 0; r < 4; ++r) l_r[r] += __shfl_xor(l_r[r], off, 64);
    float inv[4];
#pragma unroll
    for (int r = 0; r < 4; ++r) inv[r] = 1.0f / l_r[r];
#pragma unroll
    for (int db = 0; db < 8; ++db)
#pragma unroll
      for (int r = 0; r < 4; ++r)
        O[(size_t)(q0 + quad * 4 + r) * DIM + h * HD + db * 16 + row] = f2b(o_acc[db][r] * inv[r]);
  }
}

extern "C" void kernel_launch(void* const* d_in, const int* in_sizes, int n_in,
                              void* d_out, int out_size, void* d_ws, size_t ws_size,
                              hipStream_t stream) {
  const float* x    = (const float*)d_in[0];
  const float* cosf = (const float*)d_in[1];
  const float* sinf = (const float*)d_in[2];
  const float* wq = (const float*)d_in[7];
  const float* wk = (const float*)d_in[8];
  const float* wv = (const float*)d_in[9];
  const float* wo = (const float*)d_in[10];
  float* out = (float*)d_out;
  float* cache_v_out = out + 12582912;

  char* ws = (char*)d_ws;
  ushort_t* xb     = (ushort_t*)(ws + 0);          // 16.8 MB
  ushort_t* wqkvb  = (ushort_t*)(ws + 16777216);   // 50.3 MB (wq|wk|wv rows)
  ushort_t* wob    = (ushort_t*)(ws + 67108864);   // 33.6 MB
  float*    qkv32  = (float*)(ws + 100663296);     // 50.3 MB
  ushort_t* qbuf   = (ushort_t*)(ws + 150994944);  // 16.8 MB
  ushort_t* kbuf   = (ushort_t*)(ws + 167772160);  // 4.2 MB
  ushort_t* vtb    = (ushort_t*)(ws + 171966464);  // 4.2 MB
  ushort_t* attnb  = (ushort_t*)(ws + 176160768);  // 16.8 MB -> 192.9 MB total

  // 1. all converts in one launch
  cvt_all<<<24576, 256, 0, stream>>>(x, wq, wk, wv, wo, xb, wqkvb, wob);
  // 2. fused QKV projection (2048 x 6144 x 4096), 8-phase GEMM, 384 blocks
  gemm8p<<<384, 512, 0, stream>>>(xb, wqkvb, qkv32, QKVN, DIM);
  // 3. rope_q + rope_k/cache_k + zero tails in one launch; V transpose separate
  posteps<<<22528, 256, 0, stream>>>(qkv32, cosf, sinf, qbuf, kbuf, out);
  vt_cache<<<dim3(32, 16), 256, 0, stream>>>(qkv32, vtb, cache_v_out);
  // 4. attention (pair-balanced grid)
  attn<<<dim3(16, 32), 256, 0, stream>>>(qbuf, kbuf, vtb, attnb);
  // 5. output projection (2048 x 4096 x 4096), 256 blocks = 1/CU exactly
  gemm8p<<<256, 512, 0, stream>>>(attnb, wob, out, DIM, DIM);
}